// Round 6
// baseline (596.297 us; speedup 1.0000x reference)
//
#include <hip/hip_runtime.h>
#include <hip/hip_bf16.h>

#define NN 8192
#define DD 512

typedef unsigned short u16;
typedef __bf16 bf16_t;
typedef bf16_t bf16x8 __attribute__((ext_vector_type(8)));
typedef float f32x4 __attribute__((ext_vector_type(4)));

__device__ __forceinline__ float bf2f(u16 h) {
    union { unsigned u; float f; } v; v.u = ((unsigned)h) << 16; return v.f;
}
__device__ __forceinline__ float bflo(unsigned u) {
    union { unsigned u; float f; } v; v.u = u << 16; return v.f;
}
__device__ __forceinline__ float bfhi(unsigned u) {
    union { unsigned u; float f; } v; v.u = u & 0xFFFF0000u; return v.f;
}
__device__ __forceinline__ u16 f2bf(float f) {
    union { float f; unsigned u; } v; v.f = f;
    unsigned r = v.u + 0x7fffu + ((v.u >> 16) & 1u);
    return (u16)(r >> 16);
}

// fp32->bf16 convert of the 5 weight operands (x0/x1 now converted in-GEMM).
__global__ __launch_bounds__(256) void cvt5(
        const float* __restrict__ s0, u16* __restrict__ d0,
        const float* __restrict__ s1, u16* __restrict__ d1,
        const float* __restrict__ s2, u16* __restrict__ d2,
        const float* __restrict__ s3, u16* __restrict__ d3,
        const float* __restrict__ s4, u16* __restrict__ d4) {
    size_t v = ((size_t)blockIdx.x * 256 + threadIdx.x) * 8;
    const float* s; u16* d; size_t off;
    if (v < 262144)       { s = s0; d = d0; off = v; }
    else if (v < 524288)  { s = s1; d = d1; off = v - 262144; }
    else if (v < 1310720) { s = s2; d = d2; off = v - 524288; }
    else if (v < 1572864) { s = s3; d = d3; off = v - 1310720; }
    else                  { s = s4; d = d4; off = v - 1572864; }
    float4 a = *(const float4*)(s + off);
    float4 b = *(const float4*)(s + off + 4);
    ushort4 o0 = make_ushort4(f2bf(a.x), f2bf(a.y), f2bf(a.z), f2bf(a.w));
    ushort4 o1 = make_ushort4(f2bf(b.x), f2bf(b.y), f2bf(b.z), f2bf(b.w));
    *(ushort4*)(d + off) = o0;
    *(ushort4*)(d + off + 4) = o1;
}

// Modality projection GEMM: y01[16384][512] = relu(x@w^T + b) as bf16.
// A = x0 (by<64) / x1 (by>=64) read DIRECTLY as fp32 and converted during
// reg-staging (T14 issue-early/write-late); B = pre-converted weight bf16 via
// global_load_lds. Double-buffered 1-barrier pipeline.
#define EPS_LDS 136
__global__ __launch_bounds__(256) void gemm_proj(
        const float* __restrict__ X0, const float* __restrict__ X1,
        const u16* __restrict__ B0, const float* __restrict__ bias0,
        const u16* __restrict__ B1, const float* __restrict__ bias1,
        u16* __restrict__ C) {
    __shared__ alignas(16) u16 Smem[2][16384];   // 64 KB
    const int t = threadIdx.x;
    const int lane = t & 63;
    const int wave = t >> 6;
    const int wm = (wave >> 1) * 64;
    const int wn = (wave & 1) * 64;
    const int rowA = blockIdx.y * 128;           // global row 0..16383
    const int rowB = blockIdx.x * 128;
    const bool mod1 = (int)blockIdx.y >= 64;
    const float* A32 = mod1 ? X1 + (size_t)(rowA - 8192) * DD
                            : X0 + (size_t)rowA * DD;
    const u16* B = mod1 ? B1 : B0;
    const float* bias = mod1 ? bias1 : bias0;

    f32x4 acc[4][4] = {};
    const int mrow = lane & 15;
    const int kk = (lane >> 4) * 8;
    const int trow = t >> 3;
    const int koff = (t & 7) * 8;

    float ar[4][8];
    auto LOADA = [&](int k0) {
        #pragma unroll
        for (int r = 0; r < 4; ++r) {
            const float* s = A32 + (size_t)(r * 32 + trow) * DD + k0 + koff;
            float4 f0 = *(const float4*)s;
            float4 f1 = *(const float4*)(s + 4);
            ar[r][0] = f0.x; ar[r][1] = f0.y; ar[r][2] = f0.z; ar[r][3] = f0.w;
            ar[r][4] = f1.x; ar[r][5] = f1.y; ar[r][6] = f1.z; ar[r][7] = f1.w;
        }
    };
    auto WRITEA = [&](int buf) {
        u16* As = Smem[buf];
        #pragma unroll
        for (int r = 0; r < 4; ++r) {
            int chunk = r * 256 + t;
            ushort4 o0 = make_ushort4(f2bf(ar[r][0]), f2bf(ar[r][1]),
                                      f2bf(ar[r][2]), f2bf(ar[r][3]));
            ushort4 o1 = make_ushort4(f2bf(ar[r][4]), f2bf(ar[r][5]),
                                      f2bf(ar[r][6]), f2bf(ar[r][7]));
            *(ushort4*)(As + chunk * 8) = o0;
            *(ushort4*)(As + chunk * 8 + 4) = o1;
        }
    };
    auto BSTAGE = [&](int buf, int k0) {
        u16* Bs = Smem[buf] + 8192;
        #pragma unroll
        for (int r = 0; r < 4; ++r) {
            int chunk = r * 256 + t;
            const u16* srcB = B + (size_t)(rowB + (chunk >> 3)) * DD + k0 + (chunk & 7) * 8;
            __builtin_amdgcn_global_load_lds(
                (const __attribute__((address_space(1))) void*)srcB,
                (__attribute__((address_space(3))) void*)(Bs + chunk * 8), 16, 0, 0);
        }
    };

    LOADA(0); BSTAGE(0, 0); WRITEA(0);
    __syncthreads();
    int cur = 0;
    for (int ti = 0; ti < 8; ++ti) {
        if (ti < 7) { LOADA((ti + 1) << 6); BSTAGE(cur ^ 1, (ti + 1) << 6); }
        const u16* As = Smem[cur];
        const u16* Bs = Smem[cur] + 8192;
        #pragma unroll
        for (int ks = 0; ks < 64; ks += 32) {
            bf16x8 af[4], bfv[4];
            #pragma unroll
            for (int i = 0; i < 4; ++i)
                af[i] = *(const bf16x8*)(As + (wm + i * 16 + mrow) * 64 + ks + kk);
            #pragma unroll
            for (int j = 0; j < 4; ++j)
                bfv[j] = *(const bf16x8*)(Bs + (wn + j * 16 + mrow) * 64 + ks + kk);
            #pragma unroll
            for (int i = 0; i < 4; ++i)
                #pragma unroll
                for (int j = 0; j < 4; ++j)
                    acc[i][j] = __builtin_amdgcn_mfma_f32_16x16x32_bf16(af[i], bfv[j], acc[i][j], 0, 0, 0);
        }
        if (ti < 7) WRITEA(cur ^ 1);      // waits A loads; dma drains at barrier
        __syncthreads();
        cur ^= 1;
    }

    u16* Ep = &Smem[0][0];
    const int er0 = wm + (lane >> 4) * 4;
    const int ec0 = wn + (lane & 15);
    #pragma unroll
    for (int j = 0; j < 4; ++j) {
        int c = ec0 + j * 16;
        float bv = bias[rowB + c];
        #pragma unroll
        for (int i = 0; i < 4; ++i) {
            #pragma unroll
            for (int r = 0; r < 4; ++r) {
                float v = fmaxf(acc[i][j][r] + bv, 0.0f);
                Ep[(er0 + i * 16 + r) * EPS_LDS + c] = f2bf(v);
            }
        }
    }
    __syncthreads();
    #pragma unroll
    for (int pass = 0; pass < 8; ++pass) {
        int chunk = pass * 256 + t;
        int rloc = chunk >> 4, coff = (chunk & 15) * 8;
        bf16x8 v = *(const bf16x8*)(Ep + rloc * EPS_LDS + coff);
        *(bf16x8*)(C + (size_t)(rowA + rloc) * DD + rowB + coff) = v;
    }
}

// qkv GEMM, DOUBLE-BUFFERED. A = seq [16384][512], B = in_w [1536][512].
// c<8 (QK): epilogue computes per-(node,head) attention mix weights DIRECTLY:
//   the 4 combo-dots live on 4 adjacent lanes; 2 shfl_xor + softmax give
//   al_s = 0.5*(a0s+a1s), stored to AL[node][head][2] (fp32, 512 KB).
// c>=8: V cols -> V[16384][512].
__global__ __launch_bounds__(256) void gemm_qkv(const u16* __restrict__ A,
        const u16* __restrict__ B, const float* __restrict__ bias,
        u16* __restrict__ V, float* __restrict__ AL) {
    __shared__ alignas(16) u16 Smem[2][16384];   // 64 KB
    const int t = threadIdx.x;
    const int lane = t & 63;
    const int wave = t >> 6;
    const int wm = (wave >> 1) * 64;
    const int wn = (wave & 1) * 64;
    const int c = blockIdx.x;
    const int rowA = blockIdx.y * 128;
    const bool isQK = (c < 8);

    f32x4 acc[4][4] = {};
    const int mrow = lane & 15;
    const int kk = (lane >> 4) * 8;

    auto STAGE = [&](int buf, int k0) {
        u16* As = Smem[buf];
        u16* Bs = Smem[buf] + 8192;
        #pragma unroll
        for (int r = 0; r < 4; ++r) {
            int chunk = r * 256 + t;
            int rr = chunk >> 3;
            int brow = isQK ? (c * 64 + rr + ((rr >= 64) ? 448 : 0))
                            : (1024 + (c - 8) * 128 + rr);
            const u16* srcA = A + (size_t)(rowA + rr) * DD + k0 + (chunk & 7) * 8;
            __builtin_amdgcn_global_load_lds(
                (const __attribute__((address_space(1))) void*)srcA,
                (__attribute__((address_space(3))) void*)(As + chunk * 8), 16, 0, 0);
            const u16* srcB = B + (size_t)brow * DD + k0 + (chunk & 7) * 8;
            __builtin_amdgcn_global_load_lds(
                (const __attribute__((address_space(1))) void*)srcB,
                (__attribute__((address_space(3))) void*)(Bs + chunk * 8), 16, 0, 0);
        }
    };

    STAGE(0, 0);
    __syncthreads();
    int cur = 0;
    for (int ti = 0; ti < 8; ++ti) {
        if (ti + 1 < 8) STAGE(cur ^ 1, (ti + 1) << 6);
        const u16* As = Smem[cur];
        const u16* Bs = Smem[cur] + 8192;
        #pragma unroll
        for (int ks = 0; ks < 64; ks += 32) {
            bf16x8 af[4], bfv[4];
            #pragma unroll
            for (int i = 0; i < 4; ++i)
                af[i] = *(const bf16x8*)(As + (wm + i * 16 + mrow) * 64 + ks + kk);
            #pragma unroll
            for (int j = 0; j < 4; ++j)
                bfv[j] = *(const bf16x8*)(Bs + (wn + j * 16 + mrow) * 64 + ks + kk);
            #pragma unroll
            for (int i = 0; i < 4; ++i)
                #pragma unroll
                for (int j = 0; j < 4; ++j)
                    acc[i][j] = __builtin_amdgcn_mfma_f32_16x16x32_bf16(af[i], bfv[j], acc[i][j], 0, 0, 0);
        }
        __syncthreads();
        cur ^= 1;
    }

    u16* Ep = &Smem[0][0];
    const int er0 = wm + (lane >> 4) * 4;
    const int ec0 = wn + (lane & 15);
    #pragma unroll
    for (int j = 0; j < 4; ++j) {
        int cc = ec0 + j * 16;
        int bcol = isQK ? ((cc < 64) ? c * 64 + cc : 448 + c * 64 + cc)
                        : (1024 + (c - 8) * 128 + cc);
        float bv = bias[bcol];
        #pragma unroll
        for (int i = 0; i < 4; ++i) {
            #pragma unroll
            for (int r = 0; r < 4; ++r)
                Ep[(er0 + i * 16 + r) * EPS_LDS + cc] = f2bf(acc[i][j][r] + bv);
        }
    }
    __syncthreads();
    if (isQK) {
        // thread -> (node nd, combo cb): s = 0.125 * dot64(q_tt, k_ss)
        int nd = t >> 2, cb = t & 3, tt2 = cb >> 1, ss = cb & 1;
        const u16* qrow = Ep + (2 * nd + tt2) * EPS_LDS;
        const u16* krow = Ep + (2 * nd + ss) * EPS_LDS + 64;
        float s = 0.0f;
        #pragma unroll
        for (int d8 = 0; d8 < 8; ++d8) {
            bf16x8 qv = *(const bf16x8*)(qrow + d8 * 8);
            bf16x8 kv = *(const bf16x8*)(krow + d8 * 8);
            #pragma unroll
            for (int u = 0; u < 8; ++u) s += (float)qv[u] * (float)kv[u];
        }
        s *= 0.125f;
        // softmax over ss (partner = lane^1), then mean over tt (lane^2)
        float o = __shfl_xor(s, 1);
        float mm = fmaxf(s, o);
        float es = __expf(s - mm), eo = __expf(o - mm);
        float a = es / (es + eo);               // attn[tt][ss]
        float a2 = __shfl_xor(a, 2);            // attn[1-tt][ss]
        float al = 0.5f * (a + a2);             // al_ss
        if (cb < 2)
            AL[(size_t)(rowA / 2 + nd) * 16 + c * 2 + cb] = al;
    } else {
        #pragma unroll
        for (int pass = 0; pass < 8; ++pass) {
            int chunk = pass * 256 + t;
            int rloc = chunk >> 4, coff = (chunk & 15) * 8;
            bf16x8 v = *(const bf16x8*)(Ep + rloc * EPS_LDS + coff);
            *(bf16x8*)(V + (size_t)(rowA + rloc) * 512 + (c - 8) * 128 + coff) = v;
        }
    }
}

// Out-projection GEMM with FUSED attn_v: A row n = al0*V[2n] + al1*V[2n+1]
// (head of dim block = K-step index), built during reg-staging (T14).
// fused[8192][512] = ctx @ out_w^T + out_b. B = out_w bf16 via gload_lds.
__global__ __launch_bounds__(256) void gemm_outp(
        const float* __restrict__ AL, const u16* __restrict__ V,
        const u16* __restrict__ W, const float* __restrict__ bias,
        u16* __restrict__ C) {
    __shared__ alignas(16) u16 Smem[2][16384];   // 64 KB
    const int t = threadIdx.x;
    const int lane = t & 63;
    const int wave = t >> 6;
    const int wm = (wave >> 1) * 64;
    const int wn = (wave & 1) * 64;
    const int rowA = blockIdx.y * 128;
    const int rowB = blockIdx.x * 128;

    f32x4 acc[4][4] = {};
    const int mrow = lane & 15;
    const int kk = (lane >> 4) * 8;
    const int trow = t >> 3;
    const int koff = (t & 7) * 8;

    uint4 v0r[4], v1r[4];
    float2 alr[4];
    auto LOADA = [&](int ti) {               // head = ti (dims ti*64..+64)
        #pragma unroll
        for (int r = 0; r < 4; ++r) {
            int node = rowA + r * 32 + trow;
            alr[r] = *(const float2*)(AL + (size_t)node * 16 + ti * 2);
            const u16* v0p = V + (size_t)(2 * node) * 512 + ti * 64 + koff;
            v0r[r] = *(const uint4*)v0p;
            v1r[r] = *(const uint4*)(v0p + 512);
        }
    };
    auto WRITEA = [&](int buf) {
        u16* As = Smem[buf];
        #pragma unroll
        for (int r = 0; r < 4; ++r) {
            int chunk = r * 256 + t;
            union { u16 us[8]; ushort4 u4[2]; } o;
            #pragma unroll
            for (int q = 0; q < 4; ++q) {
                unsigned w0 = (&v0r[r].x)[q], w1 = (&v1r[r].x)[q];
                o.us[q * 2]     = f2bf(alr[r].x * bflo(w0) + alr[r].y * bflo(w1));
                o.us[q * 2 + 1] = f2bf(alr[r].x * bfhi(w0) + alr[r].y * bfhi(w1));
            }
            *(ushort4*)(As + chunk * 8) = o.u4[0];
            *(ushort4*)(As + chunk * 8 + 4) = o.u4[1];
        }
    };
    auto BSTAGE = [&](int buf, int k0) {
        u16* Bs = Smem[buf] + 8192;
        #pragma unroll
        for (int r = 0; r < 4; ++r) {
            int chunk = r * 256 + t;
            const u16* srcB = W + (size_t)(rowB + (chunk >> 3)) * DD + k0 + (chunk & 7) * 8;
            __builtin_amdgcn_global_load_lds(
                (const __attribute__((address_space(1))) void*)srcB,
                (__attribute__((address_space(3))) void*)(Bs + chunk * 8), 16, 0, 0);
        }
    };

    LOADA(0); BSTAGE(0, 0); WRITEA(0);
    __syncthreads();
    int cur = 0;
    for (int ti = 0; ti < 8; ++ti) {
        if (ti < 7) { LOADA(ti + 1); BSTAGE(cur ^ 1, (ti + 1) << 6); }
        const u16* As = Smem[cur];
        const u16* Bs = Smem[cur] + 8192;
        #pragma unroll
        for (int ks = 0; ks < 64; ks += 32) {
            bf16x8 af[4], bfv[4];
            #pragma unroll
            for (int i = 0; i < 4; ++i)
                af[i] = *(const bf16x8*)(As + (wm + i * 16 + mrow) * 64 + ks + kk);
            #pragma unroll
            for (int j = 0; j < 4; ++j)
                bfv[j] = *(const bf16x8*)(Bs + (wn + j * 16 + mrow) * 64 + ks + kk);
            #pragma unroll
            for (int i = 0; i < 4; ++i)
                #pragma unroll
                for (int j = 0; j < 4; ++j)
                    acc[i][j] = __builtin_amdgcn_mfma_f32_16x16x32_bf16(af[i], bfv[j], acc[i][j], 0, 0, 0);
        }
        if (ti < 7) WRITEA(cur ^ 1);
        __syncthreads();
        cur ^= 1;
    }

    u16* Ep = &Smem[0][0];
    const int er0 = wm + (lane >> 4) * 4;
    const int ec0 = wn + (lane & 15);
    #pragma unroll
    for (int j = 0; j < 4; ++j) {
        int c = ec0 + j * 16;
        float bv = bias[rowB + c];
        #pragma unroll
        for (int i = 0; i < 4; ++i) {
            #pragma unroll
            for (int r = 0; r < 4; ++r)
                Ep[(er0 + i * 16 + r) * EPS_LDS + c] = f2bf(acc[i][j][r] + bv);
        }
    }
    __syncthreads();
    #pragma unroll
    for (int pass = 0; pass < 8; ++pass) {
        int chunk = pass * 256 + t;
        int rloc = chunk >> 4, coff = (chunk & 15) * 8;
        bf16x8 v = *(const bf16x8*)(Ep + rloc * EPS_LDS + coff);
        *(bf16x8*)(C + (size_t)(rowA + rloc) * DD + rowB + coff) = v;
    }
}

// Symmetric S = F @ F^T (bf16) MERGED with hidden = relu(F @ W1^T + b1),
// DOUBLE-BUFFERED. bx < 64: sym upper-triangle; bx in {64,65}: hidden tile.
#define SYM_LDS 129
__global__ __launch_bounds__(256) void gemm_symh(const u16* __restrict__ F,
        u16* __restrict__ C, const u16* __restrict__ W1,
        const float* __restrict__ b1, u16* __restrict__ Hid) {
    __shared__ alignas(16) u16 Smem[2][16384];   // 64 KB
    const int bx = blockIdx.x, by = blockIdx.y;
    const bool isHid = (bx >= 64);
    if (!isHid && bx < by) return;
    const int t = threadIdx.x;
    const int lane = t & 63;
    const int wave = t >> 6;
    const int wm = (wave >> 1) * 64;
    const int wn = (wave & 1) * 64;
    const int rowI = by * 128;
    const int rowJ = isHid ? (bx - 64) * 128 : bx * 128;
    const u16* Bsrc = isHid ? W1 : F;

    f32x4 acc[4][4] = {};
    const int mrow = lane & 15;
    const int kk = (lane >> 4) * 8;

    auto STAGE = [&](int buf, int k0) {
        u16* As = Smem[buf];
        u16* Bs = Smem[buf] + 8192;
        #pragma unroll
        for (int r = 0; r < 4; ++r) {
            int chunk = r * 256 + t;
            const u16* srcA = F + (size_t)(rowI + (chunk >> 3)) * DD + k0 + (chunk & 7) * 8;
            __builtin_amdgcn_global_load_lds(
                (const __attribute__((address_space(1))) void*)srcA,
                (__attribute__((address_space(3))) void*)(As + chunk * 8), 16, 0, 0);
            const u16* srcB = Bsrc + (size_t)(rowJ + (chunk >> 3)) * DD + k0 + (chunk & 7) * 8;
            __builtin_amdgcn_global_load_lds(
                (const __attribute__((address_space(1))) void*)srcB,
                (__attribute__((address_space(3))) void*)(Bs + chunk * 8), 16, 0, 0);
        }
    };

    STAGE(0, 0);
    __syncthreads();
    int cur = 0;
    for (int ti = 0; ti < 8; ++ti) {
        if (ti + 1 < 8) STAGE(cur ^ 1, (ti + 1) << 6);
        const u16* As = Smem[cur];
        const u16* Bs = Smem[cur] + 8192;
        #pragma unroll
        for (int ks = 0; ks < 64; ks += 32) {
            bf16x8 af[4], bfv[4];
            #pragma unroll
            for (int i = 0; i < 4; ++i)
                af[i] = *(const bf16x8*)(As + (wm + i * 16 + mrow) * 64 + ks + kk);
            #pragma unroll
            for (int j = 0; j < 4; ++j)
                bfv[j] = *(const bf16x8*)(Bs + (wn + j * 16 + mrow) * 64 + ks + kk);
            #pragma unroll
            for (int i = 0; i < 4; ++i)
                #pragma unroll
                for (int j = 0; j < 4; ++j)
                    acc[i][j] = __builtin_amdgcn_mfma_f32_16x16x32_bf16(af[i], bfv[j], acc[i][j], 0, 0, 0);
        }
        __syncthreads();
        cur ^= 1;
    }

    u16* Ep = &Smem[0][0];
    const int er0 = wm + (lane >> 4) * 4;
    const int ec0 = wn + (lane & 15);
    #pragma unroll
    for (int j = 0; j < 4; ++j) {
        int c = ec0 + j * 16;
        float bv = isHid ? b1[rowJ + c] : 0.0f;
        #pragma unroll
        for (int i = 0; i < 4; ++i) {
            #pragma unroll
            for (int r = 0; r < 4; ++r) {
                float v = acc[i][j][r] + bv;
                if (isHid) v = fmaxf(v, 0.0f);
                Ep[(er0 + i * 16 + r) * SYM_LDS + c] = f2bf(v);
            }
        }
    }
    __syncthreads();
    if (isHid) {
        #pragma unroll
        for (int pass = 0; pass < 8; ++pass) {
            int chunk = pass * 256 + t;
            int rloc = chunk >> 4, coff = (chunk & 15) * 8;
            union { u16 us[8]; bf16x8 v; } buf;
            #pragma unroll
            for (int k = 0; k < 8; ++k) buf.us[k] = Ep[rloc * SYM_LDS + coff + k];
            *(bf16x8*)(Hid + (size_t)(rowI + rloc) * 256 + rowJ + coff) = buf.v;
        }
        return;
    }
    #pragma unroll
    for (int pass = 0; pass < 8; ++pass) {
        int chunk = pass * 256 + t;
        int rloc = chunk >> 4, coff = (chunk & 15) * 8;
        union { u16 us[8]; bf16x8 v; } buf;
        #pragma unroll
        for (int k = 0; k < 8; ++k) buf.us[k] = Ep[rloc * SYM_LDS + coff + k];
        *(bf16x8*)(C + (size_t)(rowI + rloc) * NN + rowJ + coff) = buf.v;
    }
    if (bx != by) {
        #pragma unroll
        for (int pass = 0; pass < 8; ++pass) {
            int chunk = pass * 256 + t;
            int tr = chunk >> 4, roff = (chunk & 15) * 8;
            union { u16 us[8]; bf16x8 v; } buf;
            #pragma unroll
            for (int k = 0; k < 8; ++k) buf.us[k] = Ep[(roff + k) * SYM_LDS + tr];
            *(bf16x8*)(C + (size_t)(rowJ + tr) * NN + rowI + roff) = buf.v;
        }
    }
}

// Fused LayerNorm over D=512 for BOTH modalities; wave-per-row.
__global__ __launch_bounds__(256) void ln2_kernel(const u16* __restrict__ y,
        const float* __restrict__ g0, const float* __restrict__ b0,
        const float* __restrict__ g1, const float* __restrict__ b1,
        u16* __restrict__ seq) {
    int n = blockIdx.x * 4 + (threadIdx.x >> 6);
    int lane = threadIdx.x & 63;
    int modality = n >> 13, node = n & (NN - 1);
    const float* g = modality ? g1 : g0;
    const float* b = modality ? b1 : b0;
    bf16x8 v = *(const bf16x8*)(y + (size_t)n * DD + lane * 8);
    float x[8];
    float s = 0.0f;
    #pragma unroll
    for (int u = 0; u < 8; ++u) { x[u] = (float)v[u]; s += x[u]; }
    #pragma unroll
    for (int off = 32; off; off >>= 1) s += __shfl_xor(s, off);
    float mean = s * (1.0f / DD);
    float vs = 0.0f;
    #pragma unroll
    for (int u = 0; u < 8; ++u) { x[u] -= mean; vs += x[u] * x[u]; }
    #pragma unroll
    for (int off = 32; off; off >>= 1) vs += __shfl_xor(vs, off);
    float inv = rsqrtf(vs * (1.0f / DD) + 1e-5f);
    float4 ga = *(const float4*)(g + lane * 8);
    float4 gb = *(const float4*)(g + lane * 8 + 4);
    float4 ba = *(const float4*)(b + lane * 8);
    float4 bb = *(const float4*)(b + lane * 8 + 4);
    union { u16 us[8]; bf16x8 v; } o;
    o.us[0] = f2bf(x[0] * inv * ga.x + ba.x);
    o.us[1] = f2bf(x[1] * inv * ga.y + ba.y);
    o.us[2] = f2bf(x[2] * inv * ga.z + ba.z);
    o.us[3] = f2bf(x[3] * inv * ga.w + ba.w);
    o.us[4] = f2bf(x[4] * inv * gb.x + bb.x);
    o.us[5] = f2bf(x[5] * inv * gb.y + bb.y);
    o.us[6] = f2bf(x[6] * inv * gb.z + bb.z);
    o.us[7] = f2bf(x[7] * inv * gb.w + bb.w);
    *(bf16x8*)(seq + (size_t)node * (2 * DD) + modality * DD + lane * 8) = o.v;
}

// Top-16 + softmax stats over bf16 S (blocks 0..2047, one wave/row; TOP-3
// per-lane tracking) + fused ew (blocks 2048..2175, zero own hidden rows)
// + DISTRIBUTED H-ZEROING (own Sb row + 62 KB staging slice per block).
__global__ __launch_bounds__(256) void topk_bf16(u16* __restrict__ S,
        float* __restrict__ topv, int* __restrict__ topi,
        u16* __restrict__ hidden, const float* __restrict__ w2,
        const float* __restrict__ b2, float* __restrict__ ew_out,
        float* __restrict__ H) {
    const int blk = blockIdx.x;
    const int t = threadIdx.x;
    const float4 z4 = make_float4(0.f, 0.f, 0.f, 0.f);
    if (blk >= 2048) {                    // ew blocks: 128 blocks x 64 nodes
        int wv = t >> 6, lane = t & 63;
        int n0 = (blk - 2048) * 64 + wv * 16;
        float wa = w2[lane], wb = w2[lane + 64], wc = w2[lane + 128], wd = w2[lane + 192];
        for (int q = 0; q < 16; ++q) {
            int n = n0 + q;
            const u16* hr = hidden + (size_t)n * 256;
            float s = bf2f(hr[lane]) * wa + bf2f(hr[lane + 64]) * wb
                    + bf2f(hr[lane + 128]) * wc + bf2f(hr[lane + 192]) * wd;
            #pragma unroll
            for (int off = 32; off; off >>= 1) s += __shfl_xor(s, off);
            if (lane == 0) {
                float z = s + b2[0];
                float sig = 1.0f / (1.0f + __expf(-z));
                ew_out[n] = fmaxf(sig, 1e-8f);
            }
        }
        float4* zb = (float4*)(hidden + (size_t)n0 * 256);
        #pragma unroll
        for (int i = 0; i < 8; ++i) zb[i * 64 + lane] = z4;
        return;
    }
    const float NEG = -3e38f;
    const int SENT = 0x7FFFFFFF;
    int row = blk * 4 + (t >> 6);
    int lane = t & 63;
    u16* Sr = S + (size_t)row * NN;

    float m = NEG, l = 0.0f;
    float t1v = NEG, t2v = NEG, t3v = NEG;
    int t1i = SENT, t2i = SENT, t3i = SENT;

    #pragma unroll
    for (int p = 0; p < 16; ++p) {
        uint4 raw = *(const uint4*)(Sr + p * 512 + lane * 8);
        int base = p * 512 + lane * 8;
        #pragma unroll
        for (int q = 0; q < 4; ++q) {
            unsigned w = (&raw.x)[q];
            #pragma unroll
            for (int h = 0; h < 2; ++h) {
                float x = h ? bfhi(w) : bflo(w);
                int xi = base + q * 2 + h;
                if (x > m) { l = l * __expf(m - x) + 1.0f; m = x; }
                else l += __expf(x - m);
                bool g1 = x > t1v, g2 = x > t2v, g3 = x > t3v;
                t3v = g2 ? t2v : (g3 ? x : t3v);
                t3i = g2 ? t2i : (g3 ? xi : t3i);
                t2v = g1 ? t1v : (g2 ? x : t2v);
                t2i = g1 ? t1i : (g2 ? xi : t2i);
                t1v = g1 ? x : t1v;
                t1i = g1 ? xi : t1i;
            }
        }
    }
    #pragma unroll
    for (int off = 32; off; off >>= 1) {
        float om = __shfl_xor(m, off);
        float ol = __shfl_xor(l, off);
        float nm = fmaxf(m, om);
        l = l * __expf(m - nm) + ol * __expf(om - nm);
        m = nm;
    }

    unsigned mk0 = 0, mk1 = 0, mk2 = 0, mk3 = 0;
    float c1v = t1v, c2v = t2v, c3v = t3v;
    int c1i = t1i, c2i = t2i, c3i = t3i;
    for (int r = 0; r < 16; ++r) {
        float wv = c1v; int wi = c1i;
        #pragma unroll
        for (int off = 32; off; off >>= 1) {
            float ov = __shfl_xor(wv, off);
            int oi = __shfl_xor(wi, off);
            if (ov > wv || (ov == wv && oi < wi)) { wv = ov; wi = oi; }
        }
        if (lane == 0) {
            topv[(size_t)row * 16 + r] = __expf(wv - m) / l;
            topi[(size_t)row * 16 + r] = wi;
        }
        if (wi == c1i) {
            int slot = ((wi >> 9) << 3) | (wi & 7);
            unsigned bit = 1u << (slot & 31);
            if (slot < 32) mk0 |= bit; else if (slot < 64) mk1 |= bit;
            else if (slot < 96) mk2 |= bit; else mk3 |= bit;
            c1v = c2v; c1i = c2i;
            c2v = c3v; c2i = c3i;
            c3v = NEG; c3i = SENT;
            if (c1i == SENT) {
                float nb = NEG; int ni = SENT;
                #pragma unroll
                for (int p = 0; p < 16; ++p) {
                    uint4 raw = *(const uint4*)(Sr + p * 512 + lane * 8);
                    int base = p * 512 + lane * 8;
                    #pragma unroll
                    for (int q = 0; q < 4; ++q) {
                        unsigned w = (&raw.x)[q];
                        #pragma unroll
                        for (int h = 0; h < 2; ++h) {
                            int sl = p * 8 + q * 2 + h;
                            unsigned mw = (sl < 32) ? mk0 : (sl < 64) ? mk1
                                        : (sl < 96) ? mk2 : mk3;
                            float x = ((mw >> (sl & 31)) & 1u) ? NEG
                                    : (h ? bfhi(w) : bflo(w));
                            if (x > nb) { nb = x; ni = base + q * 2 + h; }
                        }
                    }
                }
                c1v = nb; c1i = ni;
            }
        }
    }

    // zero own Sb row (16 KB): this wave is its only consumer.
    float4* srow = (float4*)Sr;
    #pragma unroll
    for (int i = 0; i < 16; ++i) srow[i * 64 + lane] = z4;

    // zero this block's 62-KB slice of dead staging H [0,104MB) U [108,128MB).
    {
        size_t vb0 = (size_t)blk * 63488;
        #pragma unroll
        for (int rr = 0; rr < 16; ++rr) {
            int j = rr * 256 + t;
            if (j < 3968) {
                size_t b = vb0 + (size_t)j * 16;
                char* p = (char*)H + (b < 109051904u ? b : b + 4194304u);
                *(float4*)p = z4;
            }
        }
    }
}

// Fused scatter + diag (exact ref semantics, race-free).
__global__ __launch_bounds__(256) void scatter_diag(const float* __restrict__ topv,
        const int* __restrict__ topi, float* __restrict__ H) {
    int tk = blockIdx.x * 256 + threadIdx.x;
    if (tk < NN * 16) {
        int i = tk >> 4;
        int idx = topi[tk];
        H[(size_t)idx * NN + i] = topv[tk];
    } else {
        int c = tk - NN * 16;
        const int* ti = topi + c * 16;
        bool self = false;
        #pragma unroll
        for (int j = 0; j < 16; ++j) self |= (ti[j] == c);
        if (!self) H[(size_t)c * NN + c] = 1.0f;
    }
}

extern "C" void kernel_launch(void* const* d_in, const int* in_sizes, int n_in,
                              void* d_out, int out_size, void* d_ws, size_t ws_size,
                              hipStream_t stream) {
    const float* x0    = (const float*)d_in[0];
    const float* x1    = (const float*)d_in[1];
    const float* w_p0  = (const float*)d_in[2];
    const float* b_p0  = (const float*)d_in[3];
    const float* g0    = (const float*)d_in[4];
    const float* beta0 = (const float*)d_in[5];
    const float* w_p1  = (const float*)d_in[6];
    const float* b_p1  = (const float*)d_in[7];
    const float* g1    = (const float*)d_in[8];
    const float* beta1 = (const float*)d_in[9];
    const float* in_w  = (const float*)d_in[10];
    const float* in_b  = (const float*)d_in[11];
    const float* out_w = (const float*)d_in[12];
    const float* out_b = (const float*)d_in[13];
    const float* ew_w1 = (const float*)d_in[14];
    const float* ew_b1 = (const float*)d_in[15];
    const float* ew_w2 = (const float*)d_in[16];
    const float* ew_b2 = (const float*)d_in[17];

    float* Hf = (float*)d_out;                  // [8192][8192] fp32 (256 MB)
    float* ew_out = Hf + (size_t)NN * NN;       // [8192] fp32

    // bf16 staging inside the fp32 H region (zeroed distributedly in topk).
    u16* Hu = (u16*)d_out;
    u16* y01    = Hu + 8388608;                 //  16..32 MB  [16384][512]
    u16* seq    = Hu + 16777216;                //  32..48 MB  [8192][2][512]
    u16* Vbuf   = Hu + 25165824;                //  48..64 MB  [16384][512]
    u16* hidden = Hu + 54525952;                // 104..108 MB [8192][256]
    float* ALb  = (float*)(Hu + 58720256);      // 112..112.5 MB AL [8192][8][2]
    u16* wp0b   = Hu + 60817408;                // 116 MB.. weights (3.25 MB)
    u16* wp1b   = wp0b + 262144;
    u16* inwb   = wp1b + 262144;                // [1536][512]
    u16* outwb  = inwb + 786432;
    u16* eww1b  = outwb + 262144;               // [256][512]
    u16* Sb     = Hu + 67108864;                // 128..256 MB raw scores bf16
    char* ws = (char*)d_ws;
    u16* fusedB = (u16*)ws;                     // [8192][512] bf16
    float* topv = (float*)(ws + (8u << 20));
    int*   topi = (int*)(ws + (8u << 20) + 524288);

    dim3 blk(256);
    // 0: fp32 -> bf16 for the 5 weight operands only
    cvt5<<<dim3(832), blk, 0, stream>>>(w_p0, wp0b, w_p1, wp1b,
                                        in_w, inwb, out_w, outwb, ew_w1, eww1b);
    // 1: both modality projections; x0/x1 converted in-staging (no x round-trip)
    gemm_proj<<<dim3(4, 128), blk, 0, stream>>>(
        x0, x1, wp0b, b_p0, wp1b, b_p1, y01);
    // 2: fused LayerNorm -> seq (wave-per-row)
    ln2_kernel<<<dim3(2 * NN / 4), blk, 0, stream>>>(y01, g0, beta0, g1, beta1, seq);
    // 3: qkv GEMM; V stored, QK -> per-(node,head) mix weights AL directly
    gemm_qkv<<<dim3(12, 128), blk, 0, stream>>>(seq, inwb, in_b, Vbuf, ALb);
    // 4: out-proj with fused attn_v (ctxm built in-staging from V + AL)
    gemm_outp<<<dim3(4, 64), blk, 0, stream>>>(ALb, Vbuf, outwb, out_b, fusedB);
    // 5: S = fused@fused^T + hidden GEMM merged (dbuf)
    gemm_symh<<<dim3(66, 64), blk, 0, stream>>>(fusedB, Sb, eww1b, ew_b1, hidden);
    // 6: top-16 + softmax stats + fused ew + distributed H-zeroing (no memset)
    topk_bf16<<<dim3(2176), blk, 0, stream>>>(Sb, topv, topi,
        hidden, ew_w2, ew_b2, ew_out, Hf);
    // 7: fused scatter + conditional diag
    scatter_diag<<<dim3((NN * 16 + NN) / 256), blk, 0, stream>>>(topv, topi, Hf);
}

// Round 7
// 570.769 us; speedup vs baseline: 1.0447x; 1.0447x over previous
//
#include <hip/hip_runtime.h>
#include <hip/hip_bf16.h>

#define NN 8192
#define DD 512

typedef unsigned short u16;
typedef __bf16 bf16_t;
typedef bf16_t bf16x8 __attribute__((ext_vector_type(8)));
typedef float f32x4 __attribute__((ext_vector_type(4)));

__device__ __forceinline__ float bf2f(u16 h) {
    union { unsigned u; float f; } v; v.u = ((unsigned)h) << 16; return v.f;
}
__device__ __forceinline__ float bflo(unsigned u) {
    union { unsigned u; float f; } v; v.u = u << 16; return v.f;
}
__device__ __forceinline__ float bfhi(unsigned u) {
    union { unsigned u; float f; } v; v.u = u & 0xFFFF0000u; return v.f;
}
__device__ __forceinline__ u16 f2bf(float f) {
    union { float f; unsigned u; } v; v.f = f;
    unsigned r = v.u + 0x7fffu + ((v.u >> 16) & 1u);
    return (u16)(r >> 16);
}

// counted-vmcnt barrier: buf[t+1] resident (4 newest loads may stay in flight).
#define PIPE_BARRIER(N) do { \
    __builtin_amdgcn_sched_barrier(0); \
    asm volatile("s_waitcnt vmcnt(" #N ")" ::: "memory"); \
    __builtin_amdgcn_s_barrier(); \
    __builtin_amdgcn_sched_barrier(0); \
} while (0)

// fp32->bf16 convert of the 5 weight operands (x0/x1 converted in-GEMM).
__global__ __launch_bounds__(256) void cvt5(
        const float* __restrict__ s0, u16* __restrict__ d0,
        const float* __restrict__ s1, u16* __restrict__ d1,
        const float* __restrict__ s2, u16* __restrict__ d2,
        const float* __restrict__ s3, u16* __restrict__ d3,
        const float* __restrict__ s4, u16* __restrict__ d4) {
    size_t v = ((size_t)blockIdx.x * 256 + threadIdx.x) * 8;
    const float* s; u16* d; size_t off;
    if (v < 262144)       { s = s0; d = d0; off = v; }
    else if (v < 524288)  { s = s1; d = d1; off = v - 262144; }
    else if (v < 1310720) { s = s2; d = d2; off = v - 524288; }
    else if (v < 1572864) { s = s3; d = d3; off = v - 1310720; }
    else                  { s = s4; d = d4; off = v - 1572864; }
    float4 a = *(const float4*)(s + off);
    float4 b = *(const float4*)(s + off + 4);
    ushort4 o0 = make_ushort4(f2bf(a.x), f2bf(a.y), f2bf(a.z), f2bf(a.w));
    ushort4 o1 = make_ushort4(f2bf(b.x), f2bf(b.y), f2bf(b.z), f2bf(b.w));
    *(ushort4*)(d + off) = o0;
    *(ushort4*)(d + off + 4) = o1;
}

// Modality projection GEMM: y01[16384][512] = relu(x@w^T + b) as bf16.
// A = x0/x1 read fp32, converted during reg-staging; dbuf 1-barrier pipeline.
#define EPS_LDS 136
__global__ __launch_bounds__(256) void gemm_proj(
        const float* __restrict__ X0, const float* __restrict__ X1,
        const u16* __restrict__ B0, const float* __restrict__ bias0,
        const u16* __restrict__ B1, const float* __restrict__ bias1,
        u16* __restrict__ C) {
    __shared__ alignas(16) u16 Smem[2][16384];   // 64 KB
    const int t = threadIdx.x;
    const int lane = t & 63;
    const int wave = t >> 6;
    const int wm = (wave >> 1) * 64;
    const int wn = (wave & 1) * 64;
    const int rowA = blockIdx.y * 128;           // global row 0..16383
    const int rowB = blockIdx.x * 128;
    const bool mod1 = (int)blockIdx.y >= 64;
    const float* A32 = mod1 ? X1 + (size_t)(rowA - 8192) * DD
                            : X0 + (size_t)rowA * DD;
    const u16* B = mod1 ? B1 : B0;
    const float* bias = mod1 ? bias1 : bias0;

    f32x4 acc[4][4] = {};
    const int mrow = lane & 15;
    const int kk = (lane >> 4) * 8;
    const int trow = t >> 3;
    const int koff = (t & 7) * 8;

    float ar[4][8];
    auto LOADA = [&](int k0) {
        #pragma unroll
        for (int r = 0; r < 4; ++r) {
            const float* s = A32 + (size_t)(r * 32 + trow) * DD + k0 + koff;
            float4 f0 = *(const float4*)s;
            float4 f1 = *(const float4*)(s + 4);
            ar[r][0] = f0.x; ar[r][1] = f0.y; ar[r][2] = f0.z; ar[r][3] = f0.w;
            ar[r][4] = f1.x; ar[r][5] = f1.y; ar[r][6] = f1.z; ar[r][7] = f1.w;
        }
    };
    auto WRITEA = [&](int buf) {
        u16* As = Smem[buf];
        #pragma unroll
        for (int r = 0; r < 4; ++r) {
            int chunk = r * 256 + t;
            ushort4 o0 = make_ushort4(f2bf(ar[r][0]), f2bf(ar[r][1]),
                                      f2bf(ar[r][2]), f2bf(ar[r][3]));
            ushort4 o1 = make_ushort4(f2bf(ar[r][4]), f2bf(ar[r][5]),
                                      f2bf(ar[r][6]), f2bf(ar[r][7]));
            *(ushort4*)(As + chunk * 8) = o0;
            *(ushort4*)(As + chunk * 8 + 4) = o1;
        }
    };
    auto BSTAGE = [&](int buf, int k0) {
        u16* Bs = Smem[buf] + 8192;
        #pragma unroll
        for (int r = 0; r < 4; ++r) {
            int chunk = r * 256 + t;
            const u16* srcB = B + (size_t)(rowB + (chunk >> 3)) * DD + k0 + (chunk & 7) * 8;
            __builtin_amdgcn_global_load_lds(
                (const __attribute__((address_space(1))) void*)srcB,
                (__attribute__((address_space(3))) void*)(Bs + chunk * 8), 16, 0, 0);
        }
    };

    LOADA(0); BSTAGE(0, 0); WRITEA(0);
    __syncthreads();
    int cur = 0;
    for (int ti = 0; ti < 8; ++ti) {
        if (ti < 7) { LOADA((ti + 1) << 6); BSTAGE(cur ^ 1, (ti + 1) << 6); }
        const u16* As = Smem[cur];
        const u16* Bs = Smem[cur] + 8192;
        #pragma unroll
        for (int ks = 0; ks < 64; ks += 32) {
            bf16x8 af[4], bfv[4];
            #pragma unroll
            for (int i = 0; i < 4; ++i)
                af[i] = *(const bf16x8*)(As + (wm + i * 16 + mrow) * 64 + ks + kk);
            #pragma unroll
            for (int j = 0; j < 4; ++j)
                bfv[j] = *(const bf16x8*)(Bs + (wn + j * 16 + mrow) * 64 + ks + kk);
            #pragma unroll
            for (int i = 0; i < 4; ++i)
                #pragma unroll
                for (int j = 0; j < 4; ++j)
                    acc[i][j] = __builtin_amdgcn_mfma_f32_16x16x32_bf16(af[i], bfv[j], acc[i][j], 0, 0, 0);
        }
        if (ti < 7) WRITEA(cur ^ 1);
        __syncthreads();
        cur ^= 1;
    }

    u16* Ep = &Smem[0][0];
    const int er0 = wm + (lane >> 4) * 4;
    const int ec0 = wn + (lane & 15);
    #pragma unroll
    for (int j = 0; j < 4; ++j) {
        int c = ec0 + j * 16;
        float bv = bias[rowB + c];
        #pragma unroll
        for (int i = 0; i < 4; ++i) {
            #pragma unroll
            for (int r = 0; r < 4; ++r) {
                float v = fmaxf(acc[i][j][r] + bv, 0.0f);
                Ep[(er0 + i * 16 + r) * EPS_LDS + c] = f2bf(v);
            }
        }
    }
    __syncthreads();
    #pragma unroll
    for (int pass = 0; pass < 8; ++pass) {
        int chunk = pass * 256 + t;
        int rloc = chunk >> 4, coff = (chunk & 15) * 8;
        bf16x8 v = *(const bf16x8*)(Ep + rloc * EPS_LDS + coff);
        *(bf16x8*)(C + (size_t)(rowA + rloc) * DD + rowB + coff) = v;
    }
}

// qkv GEMM, 3-BUF BK=32 COUNTED-VMCNT pipeline (T4): 2 stages in flight across
// every barrier, no mid-loop drain-to-0; 48 KB LDS -> 3 blocks/CU.
// c<8 (QK): epilogue -> per-(node,head) mix weights AL[node][head][2].
// c>=8: V cols -> V[16384][512].
__global__ __launch_bounds__(256) void gemm_qkv(const u16* __restrict__ A,
        const u16* __restrict__ B, const float* __restrict__ bias,
        u16* __restrict__ V, float* __restrict__ AL) {
    __shared__ alignas(16) u16 Smem[3][8192];   // 48 KB: 3 bufs {A 8K, B 8K}
    const int t = threadIdx.x;
    const int lane = t & 63;
    const int wave = t >> 6;
    const int wm = (wave >> 1) * 64;
    const int wn = (wave & 1) * 64;
    const int c = blockIdx.x;
    const int rowA = blockIdx.y * 128;
    const bool isQK = (c < 8);

    f32x4 acc[4][4] = {};
    const int mrow = lane & 15;
    const int kk = (lane >> 4) * 8;

    auto STAGE = [&](int buf, int k0) {
        u16* As = Smem[buf];
        u16* Bs = Smem[buf] + 4096;
        #pragma unroll
        for (int r = 0; r < 2; ++r) {
            int chunk = r * 256 + t;
            int rr = chunk >> 2;
            int ko = (chunk & 3) * 8;
            int brow = isQK ? (c * 64 + rr + ((rr >= 64) ? 448 : 0))
                            : (1024 + (c - 8) * 128 + rr);
            const u16* srcA = A + (size_t)(rowA + rr) * DD + k0 + ko;
            __builtin_amdgcn_global_load_lds(
                (const __attribute__((address_space(1))) void*)srcA,
                (__attribute__((address_space(3))) void*)(As + chunk * 8), 16, 0, 0);
            const u16* srcB = B + (size_t)brow * DD + k0 + ko;
            __builtin_amdgcn_global_load_lds(
                (const __attribute__((address_space(1))) void*)srcB,
                (__attribute__((address_space(3))) void*)(Bs + chunk * 8), 16, 0, 0);
        }
    };
    auto COMPUTE = [&](int buf) {
        const u16* As = Smem[buf];
        const u16* Bs = Smem[buf] + 4096;
        bf16x8 af[4], bfv[4];
        #pragma unroll
        for (int i = 0; i < 4; ++i)
            af[i] = *(const bf16x8*)(As + (wm + i * 16 + mrow) * 32 + kk);
        #pragma unroll
        for (int j = 0; j < 4; ++j)
            bfv[j] = *(const bf16x8*)(Bs + (wn + j * 16 + mrow) * 32 + kk);
        #pragma unroll
        for (int i = 0; i < 4; ++i)
            #pragma unroll
            for (int j = 0; j < 4; ++j)
                acc[i][j] = __builtin_amdgcn_mfma_f32_16x16x32_bf16(af[i], bfv[j], acc[i][j], 0, 0, 0);
    };

    STAGE(0, 0);
    STAGE(1, 32);
    PIPE_BARRIER(4);
    #pragma unroll
    for (int ts = 0; ts < 14; ++ts) {
        STAGE((ts + 2) % 3, (ts + 2) * 32);
        COMPUTE(ts % 3);
        PIPE_BARRIER(4);
    }
    COMPUTE(2);              // step 14
    PIPE_BARRIER(0);
    COMPUTE(0);              // step 15
    __syncthreads();

    // epilogue: 128x136 stage (34.8 KB of the 48 KB)
    u16* Ep = &Smem[0][0];
    const int er0 = wm + (lane >> 4) * 4;
    const int ec0 = wn + (lane & 15);
    #pragma unroll
    for (int j = 0; j < 4; ++j) {
        int cc = ec0 + j * 16;
        int bcol = isQK ? ((cc < 64) ? c * 64 + cc : 448 + c * 64 + cc)
                        : (1024 + (c - 8) * 128 + cc);
        float bv = bias[bcol];
        #pragma unroll
        for (int i = 0; i < 4; ++i) {
            #pragma unroll
            for (int r = 0; r < 4; ++r)
                Ep[(er0 + i * 16 + r) * EPS_LDS + cc] = f2bf(acc[i][j][r] + bv);
        }
    }
    __syncthreads();
    if (isQK) {
        // thread -> (node nd, combo cb): s = 0.125 * dot64(q_tt, k_ss)
        int nd = t >> 2, cb = t & 3, tt2 = cb >> 1, ss = cb & 1;
        const u16* qrow = Ep + (2 * nd + tt2) * EPS_LDS;
        const u16* krow = Ep + (2 * nd + ss) * EPS_LDS + 64;
        float s = 0.0f;
        #pragma unroll
        for (int d8 = 0; d8 < 8; ++d8) {
            bf16x8 qv = *(const bf16x8*)(qrow + d8 * 8);
            bf16x8 kv = *(const bf16x8*)(krow + d8 * 8);
            #pragma unroll
            for (int u = 0; u < 8; ++u) s += (float)qv[u] * (float)kv[u];
        }
        s *= 0.125f;
        float o = __shfl_xor(s, 1);
        float mm = fmaxf(s, o);
        float es = __expf(s - mm), eo = __expf(o - mm);
        float a = es / (es + eo);               // attn[tt][ss]
        float a2 = __shfl_xor(a, 2);            // attn[1-tt][ss]
        float al = 0.5f * (a + a2);             // al_ss
        if (cb < 2)
            AL[(size_t)(rowA / 2 + nd) * 16 + c * 2 + cb] = al;
    } else {
        #pragma unroll
        for (int pass = 0; pass < 8; ++pass) {
            int chunk = pass * 256 + t;
            int rloc = chunk >> 4, coff = (chunk & 15) * 8;
            bf16x8 v = *(const bf16x8*)(Ep + rloc * EPS_LDS + coff);
            *(bf16x8*)(V + (size_t)(rowA + rloc) * 512 + (c - 8) * 128 + coff) = v;
        }
    }
}

// Out-projection GEMM with FUSED attn_v: A row n = al0*V[2n] + al1*V[2n+1],
// built during reg-staging. fused = ctx @ out_w^T + out_b.
__global__ __launch_bounds__(256) void gemm_outp(
        const float* __restrict__ AL, const u16* __restrict__ V,
        const u16* __restrict__ W, const float* __restrict__ bias,
        u16* __restrict__ C) {
    __shared__ alignas(16) u16 Smem[2][16384];   // 64 KB
    const int t = threadIdx.x;
    const int lane = t & 63;
    const int wave = t >> 6;
    const int wm = (wave >> 1) * 64;
    const int wn = (wave & 1) * 64;
    const int rowA = blockIdx.y * 128;
    const int rowB = blockIdx.x * 128;

    f32x4 acc[4][4] = {};
    const int mrow = lane & 15;
    const int kk = (lane >> 4) * 8;
    const int trow = t >> 3;
    const int koff = (t & 7) * 8;

    uint4 v0r[4], v1r[4];
    float2 alr[4];
    auto LOADA = [&](int ti) {               // head = ti (dims ti*64..+64)
        #pragma unroll
        for (int r = 0; r < 4; ++r) {
            int node = rowA + r * 32 + trow;
            alr[r] = *(const float2*)(AL + (size_t)node * 16 + ti * 2);
            const u16* v0p = V + (size_t)(2 * node) * 512 + ti * 64 + koff;
            v0r[r] = *(const uint4*)v0p;
            v1r[r] = *(const uint4*)(v0p + 512);
        }
    };
    auto WRITEA = [&](int buf) {
        u16* As = Smem[buf];
        #pragma unroll
        for (int r = 0; r < 4; ++r) {
            int chunk = r * 256 + t;
            union { u16 us[8]; ushort4 u4[2]; } o;
            #pragma unroll
            for (int q = 0; q < 4; ++q) {
                unsigned w0 = (&v0r[r].x)[q], w1 = (&v1r[r].x)[q];
                o.us[q * 2]     = f2bf(alr[r].x * bflo(w0) + alr[r].y * bflo(w1));
                o.us[q * 2 + 1] = f2bf(alr[r].x * bfhi(w0) + alr[r].y * bfhi(w1));
            }
            *(ushort4*)(As + chunk * 8) = o.u4[0];
            *(ushort4*)(As + chunk * 8 + 4) = o.u4[1];
        }
    };
    auto BSTAGE = [&](int buf, int k0) {
        u16* Bs = Smem[buf] + 8192;
        #pragma unroll
        for (int r = 0; r < 4; ++r) {
            int chunk = r * 256 + t;
            const u16* srcB = W + (size_t)(rowB + (chunk >> 3)) * DD + k0 + (chunk & 7) * 8;
            __builtin_amdgcn_global_load_lds(
                (const __attribute__((address_space(1))) void*)srcB,
                (__attribute__((address_space(3))) void*)(Bs + chunk * 8), 16, 0, 0);
        }
    };

    LOADA(0); BSTAGE(0, 0); WRITEA(0);
    __syncthreads();
    int cur = 0;
    for (int ti = 0; ti < 8; ++ti) {
        if (ti < 7) { LOADA(ti + 1); BSTAGE(cur ^ 1, (ti + 1) << 6); }
        const u16* As = Smem[cur];
        const u16* Bs = Smem[cur] + 8192;
        #pragma unroll
        for (int ks = 0; ks < 64; ks += 32) {
            bf16x8 af[4], bfv[4];
            #pragma unroll
            for (int i = 0; i < 4; ++i)
                af[i] = *(const bf16x8*)(As + (wm + i * 16 + mrow) * 64 + ks + kk);
            #pragma unroll
            for (int j = 0; j < 4; ++j)
                bfv[j] = *(const bf16x8*)(Bs + (wn + j * 16 + mrow) * 64 + ks + kk);
            #pragma unroll
            for (int i = 0; i < 4; ++i)
                #pragma unroll
                for (int j = 0; j < 4; ++j)
                    acc[i][j] = __builtin_amdgcn_mfma_f32_16x16x32_bf16(af[i], bfv[j], acc[i][j], 0, 0, 0);
        }
        if (ti < 7) WRITEA(cur ^ 1);
        __syncthreads();
        cur ^= 1;
    }

    u16* Ep = &Smem[0][0];
    const int er0 = wm + (lane >> 4) * 4;
    const int ec0 = wn + (lane & 15);
    #pragma unroll
    for (int j = 0; j < 4; ++j) {
        int c = ec0 + j * 16;
        float bv = bias[rowB + c];
        #pragma unroll
        for (int i = 0; i < 4; ++i) {
            #pragma unroll
            for (int r = 0; r < 4; ++r)
                Ep[(er0 + i * 16 + r) * EPS_LDS + c] = f2bf(acc[i][j][r] + bv);
        }
    }
    __syncthreads();
    #pragma unroll
    for (int pass = 0; pass < 8; ++pass) {
        int chunk = pass * 256 + t;
        int rloc = chunk >> 4, coff = (chunk & 15) * 8;
        bf16x8 v = *(const bf16x8*)(Ep + rloc * EPS_LDS + coff);
        *(bf16x8*)(C + (size_t)(rowA + rloc) * DD + rowB + coff) = v;
    }
}

// Symmetric S = F @ F^T (bf16) + hidden = relu(F @ W1^T + b1) merged,
// 3-BUF BK=32 COUNTED-VMCNT pipeline; 48 KB LDS -> 3 blocks/CU.
// bx < 64: sym upper-triangle (off-diag stores twice); bx in {64,65}: hidden.
#define SYM_LDS 129
__global__ __launch_bounds__(256) void gemm_symh(const u16* __restrict__ F,
        u16* __restrict__ C, const u16* __restrict__ W1,
        const float* __restrict__ b1, u16* __restrict__ Hid) {
    __shared__ alignas(16) u16 Smem[3][8192];   // 48 KB
    const int bx = blockIdx.x, by = blockIdx.y;
    const bool isHid = (bx >= 64);
    if (!isHid && bx < by) return;
    const int t = threadIdx.x;
    const int lane = t & 63;
    const int wave = t >> 6;
    const int wm = (wave >> 1) * 64;
    const int wn = (wave & 1) * 64;
    const int rowI = by * 128;
    const int rowJ = isHid ? (bx - 64) * 128 : bx * 128;
    const u16* Bsrc = isHid ? W1 : F;

    f32x4 acc[4][4] = {};
    const int mrow = lane & 15;
    const int kk = (lane >> 4) * 8;

    auto STAGE = [&](int buf, int k0) {
        u16* As = Smem[buf];
        u16* Bs = Smem[buf] + 4096;
        #pragma unroll
        for (int r = 0; r < 2; ++r) {
            int chunk = r * 256 + t;
            int row = chunk >> 2;
            int ko = (chunk & 3) * 8;
            const u16* srcA = F + (size_t)(rowI + row) * DD + k0 + ko;
            __builtin_amdgcn_global_load_lds(
                (const __attribute__((address_space(1))) void*)srcA,
                (__attribute__((address_space(3))) void*)(As + chunk * 8), 16, 0, 0);
            const u16* srcB = Bsrc + (size_t)(rowJ + row) * DD + k0 + ko;
            __builtin_amdgcn_global_load_lds(
                (const __attribute__((address_space(1))) void*)srcB,
                (__attribute__((address_space(3))) void*)(Bs + chunk * 8), 16, 0, 0);
        }
    };
    auto COMPUTE = [&](int buf) {
        const u16* As = Smem[buf];
        const u16* Bs = Smem[buf] + 4096;
        bf16x8 af[4], bfv[4];
        #pragma unroll
        for (int i = 0; i < 4; ++i)
            af[i] = *(const bf16x8*)(As + (wm + i * 16 + mrow) * 32 + kk);
        #pragma unroll
        for (int j = 0; j < 4; ++j)
            bfv[j] = *(const bf16x8*)(Bs + (wn + j * 16 + mrow) * 32 + kk);
        #pragma unroll
        for (int i = 0; i < 4; ++i)
            #pragma unroll
            for (int j = 0; j < 4; ++j)
                acc[i][j] = __builtin_amdgcn_mfma_f32_16x16x32_bf16(af[i], bfv[j], acc[i][j], 0, 0, 0);
    };

    STAGE(0, 0);
    STAGE(1, 32);
    PIPE_BARRIER(4);
    #pragma unroll
    for (int ts = 0; ts < 14; ++ts) {
        STAGE((ts + 2) % 3, (ts + 2) * 32);
        COMPUTE(ts % 3);
        PIPE_BARRIER(4);
    }
    COMPUTE(2);              // step 14
    PIPE_BARRIER(0);
    COMPUTE(0);              // step 15
    __syncthreads();

    u16* Ep = &Smem[0][0];
    const int er0 = wm + (lane >> 4) * 4;
    const int ec0 = wn + (lane & 15);
    #pragma unroll
    for (int j = 0; j < 4; ++j) {
        int c = ec0 + j * 16;
        float bv = isHid ? b1[rowJ + c] : 0.0f;
        #pragma unroll
        for (int i = 0; i < 4; ++i) {
            #pragma unroll
            for (int r = 0; r < 4; ++r) {
                float v = acc[i][j][r] + bv;
                if (isHid) v = fmaxf(v, 0.0f);
                Ep[(er0 + i * 16 + r) * SYM_LDS + c] = f2bf(v);
            }
        }
    }
    __syncthreads();
    if (isHid) {
        #pragma unroll
        for (int pass = 0; pass < 8; ++pass) {
            int chunk = pass * 256 + t;
            int rloc = chunk >> 4, coff = (chunk & 15) * 8;
            union { u16 us[8]; bf16x8 v; } buf;
            #pragma unroll
            for (int k = 0; k < 8; ++k) buf.us[k] = Ep[rloc * SYM_LDS + coff + k];
            *(bf16x8*)(Hid + (size_t)(rowI + rloc) * 256 + rowJ + coff) = buf.v;
        }
        return;
    }
    #pragma unroll
    for (int pass = 0; pass < 8; ++pass) {
        int chunk = pass * 256 + t;
        int rloc = chunk >> 4, coff = (chunk & 15) * 8;
        union { u16 us[8]; bf16x8 v; } buf;
        #pragma unroll
        for (int k = 0; k < 8; ++k) buf.us[k] = Ep[rloc * SYM_LDS + coff + k];
        *(bf16x8*)(C + (size_t)(rowI + rloc) * NN + rowJ + coff) = buf.v;
    }
    if (bx != by) {
        #pragma unroll
        for (int pass = 0; pass < 8; ++pass) {
            int chunk = pass * 256 + t;
            int tr = chunk >> 4, roff = (chunk & 15) * 8;
            union { u16 us[8]; bf16x8 v; } buf;
            #pragma unroll
            for (int k = 0; k < 8; ++k) buf.us[k] = Ep[(roff + k) * SYM_LDS + tr];
            *(bf16x8*)(C + (size_t)(rowJ + tr) * NN + rowI + roff) = buf.v;
        }
    }
}

// Fused LayerNorm over D=512 for BOTH modalities; wave-per-row.
__global__ __launch_bounds__(256) void ln2_kernel(const u16* __restrict__ y,
        const float* __restrict__ g0, const float* __restrict__ b0,
        const float* __restrict__ g1, const float* __restrict__ b1,
        u16* __restrict__ seq) {
    int n = blockIdx.x * 4 + (threadIdx.x >> 6);
    int lane = threadIdx.x & 63;
    int modality = n >> 13, node = n & (NN - 1);
    const float* g = modality ? g1 : g0;
    const float* b = modality ? b1 : b0;
    bf16x8 v = *(const bf16x8*)(y + (size_t)n * DD + lane * 8);
    float x[8];
    float s = 0.0f;
    #pragma unroll
    for (int u = 0; u < 8; ++u) { x[u] = (float)v[u]; s += x[u]; }
    #pragma unroll
    for (int off = 32; off; off >>= 1) s += __shfl_xor(s, off);
    float mean = s * (1.0f / DD);
    float vs = 0.0f;
    #pragma unroll
    for (int u = 0; u < 8; ++u) { x[u] -= mean; vs += x[u] * x[u]; }
    #pragma unroll
    for (int off = 32; off; off >>= 1) vs += __shfl_xor(vs, off);
    float inv = rsqrtf(vs * (1.0f / DD) + 1e-5f);
    float4 ga = *(const float4*)(g + lane * 8);
    float4 gb = *(const float4*)(g + lane * 8 + 4);
    float4 ba = *(const float4*)(b + lane * 8);
    float4 bb = *(const float4*)(b + lane * 8 + 4);
    union { u16 us[8]; bf16x8 v; } o;
    o.us[0] = f2bf(x[0] * inv * ga.x + ba.x);
    o.us[1] = f2bf(x[1] * inv * ga.y + ba.y);
    o.us[2] = f2bf(x[2] * inv * ga.z + ba.z);
    o.us[3] = f2bf(x[3] * inv * ga.w + ba.w);
    o.us[4] = f2bf(x[4] * inv * gb.x + bb.x);
    o.us[5] = f2bf(x[5] * inv * gb.y + bb.y);
    o.us[6] = f2bf(x[6] * inv * gb.z + bb.z);
    o.us[7] = f2bf(x[7] * inv * gb.w + bb.w);
    *(bf16x8*)(seq + (size_t)node * (2 * DD) + modality * DD + lane * 8) = o.v;
}

// Top-16 + softmax stats over bf16 S (blocks 0..2047, one wave/row; TOP-3
// per-lane tracking) + fused ew (blocks 2048..2175, zero own hidden rows)
// + DISTRIBUTED H-ZEROING (own Sb row + 62 KB staging slice per block).
__global__ __launch_bounds__(256) void topk_bf16(u16* __restrict__ S,
        float* __restrict__ topv, int* __restrict__ topi,
        u16* __restrict__ hidden, const float* __restrict__ w2,
        const float* __restrict__ b2, float* __restrict__ ew_out,
        float* __restrict__ H) {
    const int blk = blockIdx.x;
    const int t = threadIdx.x;
    const float4 z4 = make_float4(0.f, 0.f, 0.f, 0.f);
    if (blk >= 2048) {                    // ew blocks: 128 blocks x 64 nodes
        int wv = t >> 6, lane = t & 63;
        int n0 = (blk - 2048) * 64 + wv * 16;
        float wa = w2[lane], wb = w2[lane + 64], wc = w2[lane + 128], wd = w2[lane + 192];
        for (int q = 0; q < 16; ++q) {
            int n = n0 + q;
            const u16* hr = hidden + (size_t)n * 256;
            float s = bf2f(hr[lane]) * wa + bf2f(hr[lane + 64]) * wb
                    + bf2f(hr[lane + 128]) * wc + bf2f(hr[lane + 192]) * wd;
            #pragma unroll
            for (int off = 32; off; off >>= 1) s += __shfl_xor(s, off);
            if (lane == 0) {
                float z = s + b2[0];
                float sig = 1.0f / (1.0f + __expf(-z));
                ew_out[n] = fmaxf(sig, 1e-8f);
            }
        }
        float4* zb = (float4*)(hidden + (size_t)n0 * 256);
        #pragma unroll
        for (int i = 0; i < 8; ++i) zb[i * 64 + lane] = z4;
        return;
    }
    const float NEG = -3e38f;
    const int SENT = 0x7FFFFFFF;
    int row = blk * 4 + (t >> 6);
    int lane = t & 63;
    u16* Sr = S + (size_t)row * NN;

    float m = NEG, l = 0.0f;
    float t1v = NEG, t2v = NEG, t3v = NEG;
    int t1i = SENT, t2i = SENT, t3i = SENT;

    #pragma unroll
    for (int p = 0; p < 16; ++p) {
        uint4 raw = *(const uint4*)(Sr + p * 512 + lane * 8);
        int base = p * 512 + lane * 8;
        #pragma unroll
        for (int q = 0; q < 4; ++q) {
            unsigned w = (&raw.x)[q];
            #pragma unroll
            for (int h = 0; h < 2; ++h) {
                float x = h ? bfhi(w) : bflo(w);
                int xi = base + q * 2 + h;
                if (x > m) { l = l * __expf(m - x) + 1.0f; m = x; }
                else l += __expf(x - m);
                bool g1 = x > t1v, g2 = x > t2v, g3 = x > t3v;
                t3v = g2 ? t2v : (g3 ? x : t3v);
                t3i = g2 ? t2i : (g3 ? xi : t3i);
                t2v = g1 ? t1v : (g2 ? x : t2v);
                t2i = g1 ? t1i : (g2 ? xi : t2i);
                t1v = g1 ? x : t1v;
                t1i = g1 ? xi : t1i;
            }
        }
    }
    #pragma unroll
    for (int off = 32; off; off >>= 1) {
        float om = __shfl_xor(m, off);
        float ol = __shfl_xor(l, off);
        float nm = fmaxf(m, om);
        l = l * __expf(m - nm) + ol * __expf(om - nm);
        m = nm;
    }

    unsigned mk0 = 0, mk1 = 0, mk2 = 0, mk3 = 0;
    float c1v = t1v, c2v = t2v, c3v = t3v;
    int c1i = t1i, c2i = t2i, c3i = t3i;
    for (int r = 0; r < 16; ++r) {
        float wv = c1v; int wi = c1i;
        #pragma unroll
        for (int off = 32; off; off >>= 1) {
            float ov = __shfl_xor(wv, off);
            int oi = __shfl_xor(wi, off);
            if (ov > wv || (ov == wv && oi < wi)) { wv = ov; wi = oi; }
        }
        if (lane == 0) {
            topv[(size_t)row * 16 + r] = __expf(wv - m) / l;
            topi[(size_t)row * 16 + r] = wi;
        }
        if (wi == c1i) {
            int slot = ((wi >> 9) << 3) | (wi & 7);
            unsigned bit = 1u << (slot & 31);
            if (slot < 32) mk0 |= bit; else if (slot < 64) mk1 |= bit;
            else if (slot < 96) mk2 |= bit; else mk3 |= bit;
            c1v = c2v; c1i = c2i;
            c2v = c3v; c2i = c3i;
            c3v = NEG; c3i = SENT;
            if (c1i == SENT) {
                float nb = NEG; int ni = SENT;
                #pragma unroll
                for (int p = 0; p < 16; ++p) {
                    uint4 raw = *(const uint4*)(Sr + p * 512 + lane * 8);
                    int base = p * 512 + lane * 8;
                    #pragma unroll
                    for (int q = 0; q < 4; ++q) {
                        unsigned w = (&raw.x)[q];
                        #pragma unroll
                        for (int h = 0; h < 2; ++h) {
                            int sl = p * 8 + q * 2 + h;
                            unsigned mw = (sl < 32) ? mk0 : (sl < 64) ? mk1
                                        : (sl < 96) ? mk2 : mk3;
                            float x = ((mw >> (sl & 31)) & 1u) ? NEG
                                    : (h ? bfhi(w) : bflo(w));
                            if (x > nb) { nb = x; ni = base + q * 2 + h; }
                        }
                    }
                }
                c1v = nb; c1i = ni;
            }
        }
    }

    // zero own Sb row (16 KB): this wave is its only consumer.
    float4* srow = (float4*)Sr;
    #pragma unroll
    for (int i = 0; i < 16; ++i) srow[i * 64 + lane] = z4;

    // zero this block's 62-KB slice of dead staging H [0,104MB) U [108,128MB).
    {
        size_t vb0 = (size_t)blk * 63488;
        #pragma unroll
        for (int rr = 0; rr < 16; ++rr) {
            int j = rr * 256 + t;
            if (j < 3968) {
                size_t b = vb0 + (size_t)j * 16;
                char* p = (char*)H + (b < 109051904u ? b : b + 4194304u);
                *(float4*)p = z4;
            }
        }
    }
}

// Fused scatter + diag (exact ref semantics, race-free).
__global__ __launch_bounds__(256) void scatter_diag(const float* __restrict__ topv,
        const int* __restrict__ topi, float* __restrict__ H) {
    int tk = blockIdx.x * 256 + threadIdx.x;
    if (tk < NN * 16) {
        int i = tk >> 4;
        int idx = topi[tk];
        H[(size_t)idx * NN + i] = topv[tk];
    } else {
        int c = tk - NN * 16;
        const int* ti = topi + c * 16;
        bool self = false;
        #pragma unroll
        for (int j = 0; j < 16; ++j) self |= (ti[j] == c);
        if (!self) H[(size_t)c * NN + c] = 1.0f;
    }
}

extern "C" void kernel_launch(void* const* d_in, const int* in_sizes, int n_in,
                              void* d_out, int out_size, void* d_ws, size_t ws_size,
                              hipStream_t stream) {
    const float* x0    = (const float*)d_in[0];
    const float* x1    = (const float*)d_in[1];
    const float* w_p0  = (const float*)d_in[2];
    const float* b_p0  = (const float*)d_in[3];
    const float* g0    = (const float*)d_in[4];
    const float* beta0 = (const float*)d_in[5];
    const float* w_p1  = (const float*)d_in[6];
    const float* b_p1  = (const float*)d_in[7];
    const float* g1    = (const float*)d_in[8];
    const float* beta1 = (const float*)d_in[9];
    const float* in_w  = (const float*)d_in[10];
    const float* in_b  = (const float*)d_in[11];
    const float* out_w = (const float*)d_in[12];
    const float* out_b = (const float*)d_in[13];
    const float* ew_w1 = (const float*)d_in[14];
    const float* ew_b1 = (const float*)d_in[15];
    const float* ew_w2 = (const float*)d_in[16];
    const float* ew_b2 = (const float*)d_in[17];

    float* Hf = (float*)d_out;                  // [8192][8192] fp32 (256 MB)
    float* ew_out = Hf + (size_t)NN * NN;       // [8192] fp32

    // bf16 staging inside the fp32 H region (zeroed distributedly in topk).
    u16* Hu = (u16*)d_out;
    u16* y01    = Hu + 8388608;                 //  16..32 MB  [16384][512]
    u16* seq    = Hu + 16777216;                //  32..48 MB  [8192][2][512]
    u16* Vbuf   = Hu + 25165824;                //  48..64 MB  [16384][512]
    u16* hidden = Hu + 54525952;                // 104..108 MB [8192][256]
    float* ALb  = (float*)(Hu + 58720256);      // 112..112.5 MB AL [8192][8][2]
    u16* wp0b   = Hu + 60817408;                // 116 MB.. weights (3.25 MB)
    u16* wp1b   = wp0b + 262144;
    u16* inwb   = wp1b + 262144;                // [1536][512]
    u16* outwb  = inwb + 786432;
    u16* eww1b  = outwb + 262144;               // [256][512]
    u16* Sb     = Hu + 67108864;                // 128..256 MB raw scores bf16
    char* ws = (char*)d_ws;
    u16* fusedB = (u16*)ws;                     // [8192][512] bf16
    float* topv = (float*)(ws + (8u << 20));
    int*   topi = (int*)(ws + (8u << 20) + 524288);

    dim3 blk(256);
    // 0: fp32 -> bf16 for the 5 weight operands only
    cvt5<<<dim3(832), blk, 0, stream>>>(w_p0, wp0b, w_p1, wp1b,
                                        in_w, inwb, out_w, outwb, ew_w1, eww1b);
    // 1: both modality projections; x0/x1 converted in-staging
    gemm_proj<<<dim3(4, 128), blk, 0, stream>>>(
        x0, x1, wp0b, b_p0, wp1b, b_p1, y01);
    // 2: fused LayerNorm -> seq (wave-per-row)
    ln2_kernel<<<dim3(2 * NN / 4), blk, 0, stream>>>(y01, g0, beta0, g1, beta1, seq);
    // 3: qkv GEMM (3-buf counted-vmcnt); V stored, QK -> AL directly
    gemm_qkv<<<dim3(12, 128), blk, 0, stream>>>(seq, inwb, in_b, Vbuf, ALb);
    // 4: out-proj with fused attn_v
    gemm_outp<<<dim3(4, 64), blk, 0, stream>>>(ALb, Vbuf, outwb, out_b, fusedB);
    // 5: S = fused@fused^T + hidden GEMM merged (3-buf counted-vmcnt)
    gemm_symh<<<dim3(66, 64), blk, 0, stream>>>(fusedB, Sb, eww1b, ew_b1, hidden);
    // 6: top-16 + softmax stats + fused ew + distributed H-zeroing
    topk_bf16<<<dim3(2176), blk, 0, stream>>>(Sb, topv, topi,
        hidden, ew_w2, ew_b2, ew_out, Hf);
    // 7: fused scatter + conditional diag
    scatter_diag<<<dim3((NN * 16 + NN) / 256), blk, 0, stream>>>(topv, topi, Hf);
}